// Round 11
// baseline (224.588 us; speedup 1.0000x reference)
//
#include <hip/hip_runtime.h>
#include <hip/hip_bf16.h>
#include <stdint.h>

// Problem constants
constexpr int BB = 4, TT = 2048, CC = 1024, HH = 16, DD = 64;

typedef __bf16 bf16_t;
typedef bf16_t bf16x8 __attribute__((ext_vector_type(8)));
typedef float f32x4 __attribute__((ext_vector_type(4)));

// Native cast: compiler emits v_cvt_pk_bf16_f32 for adjacent pairs (RNE).
__device__ __forceinline__ unsigned short f2bf(float f) {
    union { __bf16 h; unsigned short u; } v;
    v.h = (__bf16)f;
    return v.u;
}

__device__ __forceinline__ f32x4 mfma16(bf16x8 a, bf16x8 b, f32x4 c) {
    return __builtin_amdgcn_mfma_f32_16x16x32_bf16(a, b, c, 0, 0, 0);
}

#define LOAD_LDS16(g, l)                                                      \
    __builtin_amdgcn_global_load_lds(                                         \
        (const __attribute__((address_space(1))) void*)(g),                   \
        (__attribute__((address_space(3))) void*)(l), 16, 0, 0)

// ---------------- fused f32 -> bf16 convert for all 3 arrays ----------------
__global__ __launch_bounds__(256) void cvt_all(
    const float* __restrict__ a, long na,    // quads
    const float* __restrict__ b, long nb,    // quads
    const float* __restrict__ c, long nc,    // quads
    unsigned short* __restrict__ oa, unsigned short* __restrict__ ob,
    unsigned short* __restrict__ oc) {
    const long ntot = na + nb + nc;
    long i = (long)blockIdx.x * blockDim.x + threadIdx.x;
    const long stride = (long)gridDim.x * blockDim.x;
    for (; i < ntot; i += stride) {
        const float* src;
        unsigned short* dst;
        long q = i;
        if (q < na) { src = a; dst = oa; }
        else if (q < na + nb) { q -= na; src = b; dst = ob; }
        else { q -= na + nb; src = c; dst = oc; }
        float4 v = *(const float4*)(src + q * 4);
        ushort4 o;
        o.x = f2bf(v.x); o.y = f2bf(v.y); o.z = f2bf(v.z); o.w = f2bf(v.w);
        *(ushort4*)(dst + q * 4) = o;
    }
}

// ------- 256x128-tile 4-phase counted-vmcnt GEMM, QKV scatter epilogue ------
// BM=256, BN=128, BK=64, 512 threads (8 waves, 4M x 2N; wave owns 64x64).
// Grid 32x24 = 768 blocks = exactly 3 rounds at 1 block/CU (96 KB LDS) --
// fixes R8's 1.5-round quantization while keeping its verified schedule.
// Phases per K-tile: {kh0:n01, kh0:n23, kh1:n01, kh1:n23}, 8 MFMA each.
// Staging per phase: A-kh0'(2) / B-kh0'(1)+vmcnt(3) / A-kh1'(2) /
// B-kh1'(1)+vmcnt(3). At each wait: 6 outstanding, vmcnt(3) confirms the 3
// loads read two phases later. T2 swizzle both-sides (rule #21, R8-verified):
// linear LDS dest, source col-slot (lane&3)^((lane>>3)&3), read slot
// g^((q16>>1)&3). T5 setprio around MFMA clusters.
__global__ __launch_bounds__(512, 2) void gemm256_qkv(
    const unsigned short* __restrict__ A,    // [M][K] bf16 (x)
    const unsigned short* __restrict__ Bw,   // [N][K] bf16 (Wqkv)
    const float* __restrict__ bias,          // [N]
    unsigned short* __restrict__ qb, unsigned short* __restrict__ kb,
    unsigned short* __restrict__ vtb, int M, int N, int K) {
    __shared__ unsigned short As[2][2][256 * 32];   // [buf][kh] 64 KB
    __shared__ unsigned short Bs[2][2][128 * 32];   // [buf][kh] 32 KB
    const int tid = threadIdx.x;
    const int w = tid >> 6, lane = tid & 63;
    const int g = lane >> 4, q16 = lane & 15;
    const int wr = w >> 1, wc = w & 1;

    // XCD swizzle, mtile-major (768 % 8 == 0 -> bijective)
    const int ntiles = N >> 7;               // 24
    const int nwg = (M >> 8) * ntiles;       // 768
    const int cpx = nwg >> 3;                // 96
    const int bid = blockIdx.x;
    const int swz = (bid & 7) * cpx + (bid >> 3);
    const int mtile = swz / ntiles, ntile = swz % ntiles;
    const int mbase = mtile << 8, nbase = ntile << 7;

    f32x4 acc[4][4];
#pragma unroll
    for (int i = 0; i < 4; ++i)
#pragma unroll
        for (int j = 0; j < 4; ++j) acc[i][j] = (f32x4){0.f, 0.f, 0.f, 0.f};

    // staging: thread covers row strow (A: +128 for 2nd instr), 16B slot
    // lane&3 (linear dest); source col-slot XOR'd by (lane>>3)&3.
    const int strow = w * 16 + (lane >> 2);            // 0..127
    const int stsl = ((lane & 3) ^ ((lane >> 3) & 3)) * 8;
    auto stageA = [&](unsigned short* dstb, const unsigned short* src0) {
#pragma unroll
        for (int i = 0; i < 2; ++i) {
            const unsigned short* src =
                src0 + (long)(i * 128 + strow) * 1024 + stsl;
            LOAD_LDS16(src, dstb + i * 4096 + w * 512);
        }
    };
    auto stageB = [&](unsigned short* dstb, const unsigned short* src0) {
        const unsigned short* src = src0 + (long)strow * 1024 + stsl;
        LOAD_LDS16(src, dstb + w * 512);
    };

    const int rsl = (g ^ ((q16 >> 1) & 3)) * 8;  // read slot (shorts)
    bf16x8 af[4], bfr[2];
    auto dsA = [&](int kh, int buf) {
#pragma unroll
        for (int i = 0; i < 4; ++i) {
            const int row = wr * 64 + i * 16 + q16;
            af[i] = *(const bf16x8*)&As[buf][kh][row * 32 + rsl];
        }
    };
    auto dsB = [&](int j0, int kh, int buf) {
#pragma unroll
        for (int j = 0; j < 2; ++j) {
            const int row = wc * 64 + (j0 + j) * 16 + q16;
            bfr[j] = *(const bf16x8*)&Bs[buf][kh][row * 32 + rsl];
        }
    };

#define MFMA8(j0)                                                             \
    __builtin_amdgcn_s_setprio(1);                                            \
    _Pragma("unroll") for (int i = 0; i < 4; ++i)                             \
        _Pragma("unroll") for (int j = 0; j < 2; ++j)                         \
            acc[i][j0 + j] = mfma16(af[i], bfr[j], acc[i][j0 + j]);           \
    __builtin_amdgcn_s_setprio(0);

    const unsigned short* Ag = A + (long)mbase * K;
    const unsigned short* Bg = Bw + (long)nbase * K;

    // prologue: stage tile 0 fully, drain, barrier
    stageA(&As[0][0][0], Ag);
    stageB(&Bs[0][0][0], Bg);
    stageA(&As[0][1][0], Ag + 32);
    stageB(&Bs[0][1][0], Bg + 32);
    asm volatile("s_waitcnt vmcnt(0)" ::: "memory");
    __builtin_amdgcn_s_barrier();

    const int NT = K >> 6;                   // 16
    for (int t = 0; t < NT; ++t) {
        const int buf = t & 1, nbuf = buf ^ 1;
        const bool hasNext = (t + 1 < NT);
        const long kn = (long)(t + 1) * 64;
        // ---- p0: kh0, n0-1 ; stage A-kh0'
        dsA(0, buf);
        dsB(0, 0, buf);
        if (hasNext) stageA(&As[nbuf][0][0], Ag + kn);
        __builtin_amdgcn_s_barrier();
        MFMA8(0)
        __builtin_amdgcn_s_barrier();
        // ---- p1: kh0, n2-3 ; stage B-kh0' ; vmcnt(3)
        dsB(2, 0, buf);
        if (hasNext) {
            stageB(&Bs[nbuf][0][0], Bg + kn);
            asm volatile("s_waitcnt vmcnt(3)" ::: "memory");
        } else {
            asm volatile("s_waitcnt vmcnt(0)" ::: "memory");
        }
        __builtin_amdgcn_s_barrier();
        MFMA8(2)
        __builtin_amdgcn_s_barrier();
        // ---- p2: kh1, n0-1 ; stage A-kh1'
        dsA(1, buf);
        dsB(0, 1, buf);
        if (hasNext) stageA(&As[nbuf][1][0], Ag + kn + 32);
        __builtin_amdgcn_s_barrier();
        MFMA8(0)
        __builtin_amdgcn_s_barrier();
        // ---- p3: kh1, n2-3 ; stage B-kh1' ; vmcnt(3)
        dsB(2, 1, buf);
        if (hasNext) {
            stageB(&Bs[nbuf][1][0], Bg + kn + 32);
            asm volatile("s_waitcnt vmcnt(3)" ::: "memory");
        }
        __builtin_amdgcn_s_barrier();
        MFMA8(2)
        __builtin_amdgcn_s_barrier();
    }
#undef MFMA8

    // epilogue: bias + QKV scatter
#pragma unroll
    for (int mi = 0; mi < 4; ++mi) {
#pragma unroll
        for (int ni = 0; ni < 4; ++ni) {
            const int n = nbase + wc * 64 + ni * 16 + q16;
            const float bv = bias[n];
#pragma unroll
            for (int r = 0; r < 4; ++r) {
                const int m = mbase + wr * 64 + mi * 16 + 4 * g + r;
                const float val = acc[mi][ni][r] + bv;
                const int which = n >> 10, rem = n & 1023;
                const int h = rem >> 6, d = rem & 63;
                const int b = m >> 11, t = m & 2047;
                const long bh = (long)(b * HH + h);
                if (which == 0)
                    qb[(bh * TT + t) * DD + d] = f2bf(val * 0.125f);
                else if (which == 1)
                    kb[(bh * TT + t) * DD + d] = f2bf(val);
                else
                    vtb[(bh * DD + d) * TT + t] = f2bf(val);
            }
        }
    }
}

// ---------------- 128x128 m97 GEMM for the projection ----------------------
__global__ __launch_bounds__(256, 3) void gemm_proj(
    const unsigned short* __restrict__ A,    // [M][K] bf16
    const unsigned short* __restrict__ Bw,   // [N][K] bf16
    const float* __restrict__ bias,          // [N]
    float* __restrict__ outf, int M, int N, int K) {
    __shared__ unsigned short As[2][128 * 32];
    __shared__ unsigned short Bs[2][128 * 32];
    const int tid = threadIdx.x;
    const int w = tid >> 6, lane = tid & 63;
    const int g = lane >> 4, q16 = lane & 15;
    const int wr = w >> 1, wc = w & 1;
    const int mbase = blockIdx.x * 128;
    const int nbase = blockIdx.y * 128;
    const int srow = lane >> 2;
    const int scol = (lane & 3) * 8;

    f32x4 acc[4][4];
#pragma unroll
    for (int i = 0; i < 4; ++i)
#pragma unroll
        for (int j = 0; j < 4; ++j) acc[i][j] = (f32x4){0.f, 0.f, 0.f, 0.f};

    const int nk = K >> 5;

    auto stage = [&](int buf, int t) {
        const int k0 = t << 5;
#pragma unroll
        for (int ii = 0; ii < 2; ++ii) {
            const int i = w + ii * 4;
            const unsigned short* ga =
                A + (long)(mbase + i * 16 + srow) * K + k0 + scol;
            LOAD_LDS16(ga, &As[buf][i * 512]);
            const unsigned short* gb =
                Bw + (long)(nbase + i * 16 + srow) * K + k0 + scol;
            LOAD_LDS16(gb, &Bs[buf][i * 512]);
        }
    };

    stage(0, 0);
    __syncthreads();
    int cur = 0;
    for (int t = 0; t < nk; ++t) {
        if (t + 1 < nk) stage(cur ^ 1, t + 1);
        bf16x8 af[4], bfr[4];
#pragma unroll
        for (int mi = 0; mi < 4; ++mi)
            af[mi] = *(const bf16x8*)&As[cur][(wr * 64 + mi * 16 + q16) * 32 + 8 * g];
#pragma unroll
        for (int ni = 0; ni < 4; ++ni)
            bfr[ni] = *(const bf16x8*)&Bs[cur][(wc * 64 + ni * 16 + q16) * 32 + 8 * g];
#pragma unroll
        for (int mi = 0; mi < 4; ++mi)
#pragma unroll
            for (int ni = 0; ni < 4; ++ni)
                acc[mi][ni] = mfma16(af[mi], bfr[ni], acc[mi][ni]);
        __syncthreads();
        cur ^= 1;
    }

#pragma unroll
    for (int mi = 0; mi < 4; ++mi) {
#pragma unroll
        for (int ni = 0; ni < 4; ++ni) {
            const int n = nbase + wc * 64 + ni * 16 + q16;
            const float bv = bias[n];
#pragma unroll
            for (int r = 0; r < 4; ++r) {
                const int m = mbase + wr * 64 + mi * 16 + 4 * g + r;
                outf[(long)m * N + n] = acc[mi][ni][r] + bv;
            }
        }
    }
}

// ---------------- causal flash attention (R5-exact structure) ---------------
__global__ __launch_bounds__(256, 4) void attn_fwd(
    const unsigned short* __restrict__ qb, const unsigned short* __restrict__ kb,
    const unsigned short* __restrict__ vtb, unsigned short* __restrict__ attb) {
    __shared__ __align__(16) unsigned short Ks[2][64 * 64];
    __shared__ __align__(16) unsigned short Vs[2][64 * 64];
    __shared__ __align__(16) unsigned short plds[4][16 * 64];
    const int tid = threadIdx.x;
    const int w = tid >> 6, lane = tid & 63;
    const int g = lane >> 4, q16 = lane & 15;
    const int bid = blockIdx.x;
    const int swz = (bid & 7) * 256 + (bid >> 3);   // 2048 % 8 == 0: bijective
    const int bx = swz & 31, bh = swz >> 5;
    const int b = bh >> 4, h = bh & 15;
    const int qbase = bx * 64 + w * 16;

    const unsigned short* Q = qb + (long)bh * TT * DD;
    const unsigned short* Kp = kb + (long)bh * TT * DD;
    const unsigned short* Vt = vtb + (long)bh * DD * TT;

    const int srow = tid >> 3;                       // 0..31
    const int ssl = ((tid & 7) ^ (srow & 7)) * 8;    // swizzled col (shorts)
    unsigned short* kdst0 = &Ks[0][0] + w * 512;     // wave-uniform dests
    unsigned short* vdst0 = &Vs[0][0] + w * 512;

    auto stageKV = [&](int buf, int kt) {
        const long kb0 = (long)kt * 64;
        const unsigned short* gk = Kp + (kb0 + srow) * DD + ssl;
        const unsigned short* gv = Vt + (long)srow * TT + kb0 + ssl;
        unsigned short* kd = kdst0 + buf * 4096;
        unsigned short* vd = vdst0 + buf * 4096;
        LOAD_LDS16(gk, kd);
        LOAD_LDS16(gk + 32l * DD, kd + 2048);
        LOAD_LDS16(gv, vd);
        LOAD_LDS16(gv + 32l * TT, vd + 2048);
    };

    bf16x8 aq0 = *(const bf16x8*)&Q[(qbase + q16) * DD + 8 * g];
    bf16x8 aq1 = *(const bf16x8*)&Q[(qbase + q16) * DD + 32 + 8 * g];

    f32x4 acc[4];
#pragma unroll
    for (int i = 0; i < 4; ++i) acc[i] = (f32x4){0.f, 0.f, 0.f, 0.f};
    float mrow = -1e30f, lrow = 0.f;

    const int slot0 = (g ^ (q16 & 7)) << 3;
    const int nkt = bx + 1;
    stageKV(0, 0);
    __syncthreads();
    int cur = 0;
    for (int kt = 0; kt < nkt; ++kt) {
        if (kt + 1 < nkt) stageKV(cur ^ 1, kt + 1);
        const int kbase = kt * 64;
        f32x4 p[4];
#pragma unroll
        for (int s = 0; s < 4; ++s) p[s] = (f32x4){0.f, 0.f, 0.f, 0.f};
#pragma unroll
        for (int s = 0; s < 4; ++s) {
            const int kr = (16 * s + q16) * 64;
            bf16x8 bk0 = *(const bf16x8*)&Ks[cur][kr + slot0];
            bf16x8 bk1 = *(const bf16x8*)&Ks[cur][kr + (slot0 ^ 32)];
            p[s] = mfma16(bk0, aq0, p[s]);
            p[s] = mfma16(bk1, aq1, p[s]);
        }
        const int q = qbase + q16;
        if (kt == nkt - 1) {
#pragma unroll
            for (int s = 0; s < 4; ++s)
#pragma unroll
                for (int r = 0; r < 4; ++r)
                    if (kbase + 16 * s + 4 * g + r > q) p[s][r] = -1e30f;
        }
        float t = fmaxf(fmaxf(p[0][0], p[0][1]), fmaxf(p[0][2], p[0][3]));
#pragma unroll
        for (int s = 1; s < 4; ++s)
            t = fmaxf(t, fmaxf(fmaxf(p[s][0], p[s][1]), fmaxf(p[s][2], p[s][3])));
        t = fmaxf(t, __shfl_xor(t, 16));
        t = fmaxf(t, __shfl_xor(t, 32));
        if (__all(t - mrow <= 8.0f)) {
            float ssum = 0.f;
#pragma unroll
            for (int s = 0; s < 4; ++s)
#pragma unroll
                for (int r = 0; r < 4; ++r) {
                    p[s][r] = __expf(p[s][r] - mrow);
                    ssum += p[s][r];
                }
            ssum += __shfl_xor(ssum, 16);
            ssum += __shfl_xor(ssum, 32);
            lrow += ssum;
        } else {
            const float nm = fmaxf(mrow, t);
            const float fs = __expf(mrow - nm);
            mrow = nm;
            float ssum = 0.f;
#pragma unroll
            for (int s = 0; s < 4; ++s)
#pragma unroll
                for (int r = 0; r < 4; ++r) {
                    p[s][r] = __expf(p[s][r] - nm);
                    ssum += p[s][r];
                }
            ssum += __shfl_xor(ssum, 16);
            ssum += __shfl_xor(ssum, 32);
            lrow = lrow * fs + ssum;
            float fr[4];
#pragma unroll
            for (int r = 0; r < 4; ++r) fr[r] = __shfl(fs, 4 * g + r);
#pragma unroll
            for (int ni = 0; ni < 4; ++ni)
#pragma unroll
                for (int r = 0; r < 4; ++r) acc[ni][r] *= fr[r];
        }
#pragma unroll
        for (int s = 0; s < 4; ++s) {
            ushort4 pk;
            pk.x = f2bf(p[s][0]); pk.y = f2bf(p[s][1]);
            pk.z = f2bf(p[s][2]); pk.w = f2bf(p[s][3]);
            const int Gp = ((2 * s + (g >> 1)) ^ (q16 & 7)) * 8 + (g & 1) * 4;
            *(ushort4*)&plds[w][q16 * 64 + Gp] = pk;
        }
        bf16x8 pa0 = *(const bf16x8*)&plds[w][q16 * 64 + slot0];
        bf16x8 pa1 = *(const bf16x8*)&plds[w][q16 * 64 + (slot0 ^ 32)];
#pragma unroll
        for (int ni = 0; ni < 4; ++ni) {
            const int vr = (ni * 16 + q16) * 64;
            bf16x8 bv0 = *(const bf16x8*)&Vs[cur][vr + slot0];
            bf16x8 bv1 = *(const bf16x8*)&Vs[cur][vr + (slot0 ^ 32)];
            acc[ni] = mfma16(pa0, bv0, acc[ni]);
            acc[ni] = mfma16(pa1, bv1, acc[ni]);
        }
        __syncthreads();
        cur ^= 1;
    }
    float inv[4];
#pragma unroll
    for (int r = 0; r < 4; ++r) inv[r] = 1.0f / __shfl(lrow, 4 * g + r);
#pragma unroll
    for (int ni = 0; ni < 4; ++ni)
#pragma unroll
        for (int r = 0; r < 4; ++r) {
            const int q = qbase + 4 * g + r;
            const int d = ni * 16 + q16;
            attb[(((long)b * TT + q) * HH + h) * DD + d] =
                f2bf(acc[ni][r] * inv[r]);
        }
}

extern "C" void kernel_launch(void* const* d_in, const int* in_sizes, int n_in,
                              void* d_out, int out_size, void* d_ws, size_t ws_size,
                              hipStream_t stream) {
    const float* x = (const float*)d_in[0];
    const float* Wqkv = (const float*)d_in[1];
    const float* bqkv = (const float*)d_in[2];
    const float* Wproj = (const float*)d_in[3];
    const float* bproj = (const float*)d_in[4];
    float* out = (float*)d_out;

    char* ws = (char*)d_ws;
    unsigned short* xb = (unsigned short*)(ws);                  // 16 MB (reused as attb)
    unsigned short* wqkvb = (unsigned short*)(ws + (16l << 20)); // 6 MB
    unsigned short* wprojb = (unsigned short*)(ws + (22l << 20));// 2 MB
    unsigned short* qb = (unsigned short*)(ws + (24l << 20));    // 16 MB
    unsigned short* kb = (unsigned short*)(ws + (40l << 20));    // 16 MB
    unsigned short* vtb = (unsigned short*)(ws + (56l << 20));   // 16 MB
    unsigned short* attb = xb;  // x dead after QKV GEMM; reuse

    cvt_all<<<2048, 256, 0, stream>>>(
        x, (long)BB * TT * CC / 4, Wqkv, (long)3 * CC * CC / 4, Wproj,
        (long)CC * CC / 4, xb, wqkvb, wprojb);

    gemm256_qkv<<<768, 512, 0, stream>>>(xb, wqkvb, bqkv, qb, kb, vtb,
                                         BB * TT, 3 * CC, CC);
    attn_fwd<<<2048, 256, 0, stream>>>(qb, kb, vtb, attb);
    gemm_proj<<<dim3(64, 8), 256, 0, stream>>>(attb, wprojb, bproj, out,
                                               BB * TT, CC, CC);
}

// Round 12
// 208.295 us; speedup vs baseline: 1.0782x; 1.0782x over previous
//
#include <hip/hip_runtime.h>
#include <hip/hip_bf16.h>
#include <stdint.h>

// Problem constants
constexpr int BB = 4, TT = 2048, CC = 1024, HH = 16, DD = 64;

typedef __bf16 bf16_t;
typedef bf16_t bf16x8 __attribute__((ext_vector_type(8)));
typedef float f32x4 __attribute__((ext_vector_type(4)));

// Native cast: compiler emits v_cvt_pk_bf16_f32 for adjacent pairs (RNE).
__device__ __forceinline__ unsigned short f2bf(float f) {
    union { __bf16 h; unsigned short u; } v;
    v.h = (__bf16)f;
    return v.u;
}

__device__ __forceinline__ f32x4 mfma16(bf16x8 a, bf16x8 b, f32x4 c) {
    return __builtin_amdgcn_mfma_f32_16x16x32_bf16(a, b, c, 0, 0, 0);
}

#define LOAD_LDS16(g, l)                                                      \
    __builtin_amdgcn_global_load_lds(                                         \
        (const __attribute__((address_space(1))) void*)(g),                   \
        (__attribute__((address_space(3))) void*)(l), 16, 0, 0)

// ---------------- fused f32 -> bf16 convert for all 3 arrays ----------------
__global__ __launch_bounds__(256) void cvt_all(
    const float* __restrict__ a, long na,    // quads
    const float* __restrict__ b, long nb,    // quads
    const float* __restrict__ c, long nc,    // quads
    unsigned short* __restrict__ oa, unsigned short* __restrict__ ob,
    unsigned short* __restrict__ oc) {
    const long ntot = na + nb + nc;
    long i = (long)blockIdx.x * blockDim.x + threadIdx.x;
    const long stride = (long)gridDim.x * blockDim.x;
    for (; i < ntot; i += stride) {
        const float* src;
        unsigned short* dst;
        long q = i;
        if (q < na) { src = a; dst = oa; }
        else if (q < na + nb) { q -= na; src = b; dst = ob; }
        else { q -= na + nb; src = c; dst = oc; }
        float4 v = *(const float4*)(src + q * 4);
        ushort4 o;
        o.x = f2bf(v.x); o.y = f2bf(v.y); o.z = f2bf(v.z); o.w = f2bf(v.w);
        *(ushort4*)(dst + q * 4) = o;
    }
}

// ---------------- GEMM: C[m,n] = sum_k A[m,k]*Bw[n,k] + bias[n] ----------------
// m97 structure: 128x128 tile, BK=32, 4 waves, global_load_lds(16B), dbuf LDS.
// __launch_bounds__(256,3): pin 3 blocks/CU (R10-verified: -4 us vs (256,2)).
// R8 (256^2, 1.5 rounds) and R11 (256x128, 3 rounds, 4-phase) both lost to
// this at K=1024: 16 K-tiles never amortize the deep pipeline's prologue, and
// 1 block/CU forfeits cross-block overlap. Do not restructure again.
// MODE 0: QKV epilogue -> scatter q*0.125, k to [BH][T][D], v^T to [BH][D][T]
// MODE 1: f32 out[m*N+n]
template <int MODE>
__global__ __launch_bounds__(256, 3) void gemm_bt(
    const unsigned short* __restrict__ A,    // [M][K] bf16
    const unsigned short* __restrict__ Bw,   // [N][K] bf16
    const float* __restrict__ bias,          // [N]
    unsigned short* __restrict__ qb, unsigned short* __restrict__ kb,
    unsigned short* __restrict__ vtb, float* __restrict__ outf,
    int M, int N, int K) {
    __shared__ unsigned short As[2][128 * 32];
    __shared__ unsigned short Bs[2][128 * 32];
    const int tid = threadIdx.x;
    const int w = tid >> 6, lane = tid & 63;
    const int g = lane >> 4, q16 = lane & 15;
    const int wr = w >> 1, wc = w & 1;
    const int mbase = blockIdx.x * 128;
    const int nbase = blockIdx.y * 128;
    const int srow = lane >> 2;
    const int scol = (lane & 3) * 8;

    f32x4 acc[4][4];
#pragma unroll
    for (int i = 0; i < 4; ++i)
#pragma unroll
        for (int j = 0; j < 4; ++j) acc[i][j] = (f32x4){0.f, 0.f, 0.f, 0.f};

    const int nk = K >> 5;

    auto stage = [&](int buf, int t) {
        const int k0 = t << 5;
#pragma unroll
        for (int ii = 0; ii < 2; ++ii) {
            const int i = w + ii * 4;
            const unsigned short* ga =
                A + (long)(mbase + i * 16 + srow) * K + k0 + scol;
            LOAD_LDS16(ga, &As[buf][i * 512]);
            const unsigned short* gb =
                Bw + (long)(nbase + i * 16 + srow) * K + k0 + scol;
            LOAD_LDS16(gb, &Bs[buf][i * 512]);
        }
    };

    stage(0, 0);
    __syncthreads();
    int cur = 0;
    for (int t = 0; t < nk; ++t) {
        if (t + 1 < nk) stage(cur ^ 1, t + 1);
        bf16x8 af[4], bfr[4];
#pragma unroll
        for (int mi = 0; mi < 4; ++mi)
            af[mi] = *(const bf16x8*)&As[cur][(wr * 64 + mi * 16 + q16) * 32 + 8 * g];
#pragma unroll
        for (int ni = 0; ni < 4; ++ni)
            bfr[ni] = *(const bf16x8*)&Bs[cur][(wc * 64 + ni * 16 + q16) * 32 + 8 * g];
#pragma unroll
        for (int mi = 0; mi < 4; ++mi)
#pragma unroll
            for (int ni = 0; ni < 4; ++ni)
                acc[mi][ni] = mfma16(af[mi], bfr[ni], acc[mi][ni]);
        __syncthreads();
        cur ^= 1;
    }

#pragma unroll
    for (int mi = 0; mi < 4; ++mi) {
#pragma unroll
        for (int ni = 0; ni < 4; ++ni) {
            const int n = nbase + wc * 64 + ni * 16 + q16;
            const float bv = bias[n];
#pragma unroll
            for (int r = 0; r < 4; ++r) {
                const int m = mbase + wr * 64 + mi * 16 + 4 * g + r;
                const float val = acc[mi][ni][r] + bv;
                if (MODE == 0) {
                    const int which = n >> 10, rem = n & 1023;
                    const int h = rem >> 6, d = rem & 63;
                    const int b = m >> 11, t = m & 2047;
                    const long bh = (long)(b * HH + h);
                    if (which == 0)
                        qb[(bh * TT + t) * DD + d] = f2bf(val * 0.125f);
                    else if (which == 1)
                        kb[(bh * TT + t) * DD + d] = f2bf(val);
                    else
                        vtb[(bh * DD + d) * TT + t] = f2bf(val);
                } else {
                    outf[(long)m * N + n] = val;
                }
            }
        }
    }
}

// ---------------- causal flash attention (R5 structure + LPT + setprio) -----
// grid: flat 2048 blocks, XCD-swizzled (each XCD owns 8 bh -> K+V = 4MB = L2).
// LPT ordering: bx = 31 - (swz & 31) -> longest blocks (work ~ bx+1) dispatch
// FIRST; short blocks pack the drain tail (R5's ascending order left the
// bx=31 stragglers for last -> 26% time-avg occupancy).
// T5 setprio(1) around QK and PV MFMA clusters (m191: attn +4-7%).
// Everything else R5-exact: swapped QK^T, defer-max THR=8, source-XOR-swizzled
// global_load_lds staging, plds stride-64 XOR, LDS 40960 B = 4 blocks/CU.
__global__ __launch_bounds__(256, 4) void attn_fwd(
    const unsigned short* __restrict__ qb, const unsigned short* __restrict__ kb,
    const unsigned short* __restrict__ vtb, unsigned short* __restrict__ attb) {
    __shared__ __align__(16) unsigned short Ks[2][64 * 64];
    __shared__ __align__(16) unsigned short Vs[2][64 * 64];
    __shared__ __align__(16) unsigned short plds[4][16 * 64];
    const int tid = threadIdx.x;
    const int w = tid >> 6, lane = tid & 63;
    const int g = lane >> 4, q16 = lane & 15;
    const int bid = blockIdx.x;
    const int swz = (bid & 7) * 256 + (bid >> 3);   // 2048 % 8 == 0: bijective
    const int bx = 31 - (swz & 31);                 // LPT: big bx first
    const int bh = swz >> 5;
    const int b = bh >> 4, h = bh & 15;
    const int qbase = bx * 64 + w * 16;

    const unsigned short* Q = qb + (long)bh * TT * DD;
    const unsigned short* Kp = kb + (long)bh * TT * DD;
    const unsigned short* Vt = vtb + (long)bh * DD * TT;

    const int srow = tid >> 3;                       // 0..31
    const int ssl = ((tid & 7) ^ (srow & 7)) * 8;    // swizzled col (shorts)
    unsigned short* kdst0 = &Ks[0][0] + w * 512;     // wave-uniform dests
    unsigned short* vdst0 = &Vs[0][0] + w * 512;

    auto stageKV = [&](int buf, int kt) {
        const long kb0 = (long)kt * 64;
        const unsigned short* gk = Kp + (kb0 + srow) * DD + ssl;
        const unsigned short* gv = Vt + (long)srow * TT + kb0 + ssl;
        unsigned short* kd = kdst0 + buf * 4096;
        unsigned short* vd = vdst0 + buf * 4096;
        LOAD_LDS16(gk, kd);
        LOAD_LDS16(gk + 32l * DD, kd + 2048);
        LOAD_LDS16(gv, vd);
        LOAD_LDS16(gv + 32l * TT, vd + 2048);
    };

    bf16x8 aq0 = *(const bf16x8*)&Q[(qbase + q16) * DD + 8 * g];
    bf16x8 aq1 = *(const bf16x8*)&Q[(qbase + q16) * DD + 32 + 8 * g];

    f32x4 acc[4];
#pragma unroll
    for (int i = 0; i < 4; ++i) acc[i] = (f32x4){0.f, 0.f, 0.f, 0.f};
    float mrow = -1e30f, lrow = 0.f;

    const int slot0 = (g ^ (q16 & 7)) << 3;
    const int nkt = bx + 1;
    stageKV(0, 0);
    __syncthreads();
    int cur = 0;
    for (int kt = 0; kt < nkt; ++kt) {
        if (kt + 1 < nkt) stageKV(cur ^ 1, kt + 1);
        const int kbase = kt * 64;
        f32x4 p[4];
#pragma unroll
        for (int s = 0; s < 4; ++s) p[s] = (f32x4){0.f, 0.f, 0.f, 0.f};
        __builtin_amdgcn_s_setprio(1);
#pragma unroll
        for (int s = 0; s < 4; ++s) {
            const int kr = (16 * s + q16) * 64;
            bf16x8 bk0 = *(const bf16x8*)&Ks[cur][kr + slot0];
            bf16x8 bk1 = *(const bf16x8*)&Ks[cur][kr + (slot0 ^ 32)];
            p[s] = mfma16(bk0, aq0, p[s]);
            p[s] = mfma16(bk1, aq1, p[s]);
        }
        __builtin_amdgcn_s_setprio(0);
        const int q = qbase + q16;
        if (kt == nkt - 1) {
#pragma unroll
            for (int s = 0; s < 4; ++s)
#pragma unroll
                for (int r = 0; r < 4; ++r)
                    if (kbase + 16 * s + 4 * g + r > q) p[s][r] = -1e30f;
        }
        float t = fmaxf(fmaxf(p[0][0], p[0][1]), fmaxf(p[0][2], p[0][3]));
#pragma unroll
        for (int s = 1; s < 4; ++s)
            t = fmaxf(t, fmaxf(fmaxf(p[s][0], p[s][1]), fmaxf(p[s][2], p[s][3])));
        t = fmaxf(t, __shfl_xor(t, 16));
        t = fmaxf(t, __shfl_xor(t, 32));
        if (__all(t - mrow <= 8.0f)) {
            float ssum = 0.f;
#pragma unroll
            for (int s = 0; s < 4; ++s)
#pragma unroll
                for (int r = 0; r < 4; ++r) {
                    p[s][r] = __expf(p[s][r] - mrow);
                    ssum += p[s][r];
                }
            ssum += __shfl_xor(ssum, 16);
            ssum += __shfl_xor(ssum, 32);
            lrow += ssum;
        } else {
            const float nm = fmaxf(mrow, t);
            const float fs = __expf(mrow - nm);
            mrow = nm;
            float ssum = 0.f;
#pragma unroll
            for (int s = 0; s < 4; ++s)
#pragma unroll
                for (int r = 0; r < 4; ++r) {
                    p[s][r] = __expf(p[s][r] - nm);
                    ssum += p[s][r];
                }
            ssum += __shfl_xor(ssum, 16);
            ssum += __shfl_xor(ssum, 32);
            lrow = lrow * fs + ssum;
            float fr[4];
#pragma unroll
            for (int r = 0; r < 4; ++r) fr[r] = __shfl(fs, 4 * g + r);
#pragma unroll
            for (int ni = 0; ni < 4; ++ni)
#pragma unroll
                for (int r = 0; r < 4; ++r) acc[ni][r] *= fr[r];
        }
#pragma unroll
        for (int s = 0; s < 4; ++s) {
            ushort4 pk;
            pk.x = f2bf(p[s][0]); pk.y = f2bf(p[s][1]);
            pk.z = f2bf(p[s][2]); pk.w = f2bf(p[s][3]);
            const int Gp = ((2 * s + (g >> 1)) ^ (q16 & 7)) * 8 + (g & 1) * 4;
            *(ushort4*)&plds[w][q16 * 64 + Gp] = pk;
        }
        bf16x8 pa0 = *(const bf16x8*)&plds[w][q16 * 64 + slot0];
        bf16x8 pa1 = *(const bf16x8*)&plds[w][q16 * 64 + (slot0 ^ 32)];
        __builtin_amdgcn_s_setprio(1);
#pragma unroll
        for (int ni = 0; ni < 4; ++ni) {
            const int vr = (ni * 16 + q16) * 64;
            bf16x8 bv0 = *(const bf16x8*)&Vs[cur][vr + slot0];
            bf16x8 bv1 = *(const bf16x8*)&Vs[cur][vr + (slot0 ^ 32)];
            acc[ni] = mfma16(pa0, bv0, acc[ni]);
            acc[ni] = mfma16(pa1, bv1, acc[ni]);
        }
        __builtin_amdgcn_s_setprio(0);
        __syncthreads();
        cur ^= 1;
    }
    float inv[4];
#pragma unroll
    for (int r = 0; r < 4; ++r) inv[r] = 1.0f / __shfl(lrow, 4 * g + r);
#pragma unroll
    for (int ni = 0; ni < 4; ++ni)
#pragma unroll
        for (int r = 0; r < 4; ++r) {
            const int q = qbase + 4 * g + r;
            const int d = ni * 16 + q16;
            attb[(((long)b * TT + q) * HH + h) * DD + d] =
                f2bf(acc[ni][r] * inv[r]);
        }
}

extern "C" void kernel_launch(void* const* d_in, const int* in_sizes, int n_in,
                              void* d_out, int out_size, void* d_ws, size_t ws_size,
                              hipStream_t stream) {
    const float* x = (const float*)d_in[0];
    const float* Wqkv = (const float*)d_in[1];
    const float* bqkv = (const float*)d_in[2];
    const float* Wproj = (const float*)d_in[3];
    const float* bproj = (const float*)d_in[4];
    float* out = (float*)d_out;

    char* ws = (char*)d_ws;
    unsigned short* xb = (unsigned short*)(ws);                  // 16 MB (reused as attb)
    unsigned short* wqkvb = (unsigned short*)(ws + (16l << 20)); // 6 MB
    unsigned short* wprojb = (unsigned short*)(ws + (22l << 20));// 2 MB
    unsigned short* qb = (unsigned short*)(ws + (24l << 20));    // 16 MB
    unsigned short* kb = (unsigned short*)(ws + (40l << 20));    // 16 MB
    unsigned short* vtb = (unsigned short*)(ws + (56l << 20));   // 16 MB
    unsigned short* attb = xb;  // x dead after QKV GEMM; reuse

    cvt_all<<<2048, 256, 0, stream>>>(
        x, (long)BB * TT * CC / 4, Wqkv, (long)3 * CC * CC / 4, Wproj,
        (long)CC * CC / 4, xb, wqkvb, wprojb);

    gemm_bt<0><<<dim3(64, 24), 256, 0, stream>>>(xb, wqkvb, bqkv, qb, kb, vtb,
                                                 nullptr, BB * TT, 3 * CC, CC);
    attn_fwd<<<2048, 256, 0, stream>>>(qb, kb, vtb, attb);
    gemm_bt<1><<<dim3(64, 8), 256, 0, stream>>>(attb, wprojb, bproj, nullptr,
                                                nullptr, nullptr, out, BB * TT,
                                                CC, CC);
}